// Round 12
// baseline (98.931 us; speedup 1.0000x reference)
//
#include <hip/hip_runtime.h>
#include <hip/hip_bf16.h>
#include <math.h>

#define NB 32
#define NL 128
#define ND 128

typedef __attribute__((ext_vector_type(8))) short bf16x8;
typedef __attribute__((ext_vector_type(4))) float f32x4;

union F4  { float4 v; float f[4]; };
union BF8 { bf16x8 v; ushort u[8]; };

__device__ inline ushort f2bf(float f) {
    __hip_bfloat16 h = __float2bfloat16(f);
    union { __hip_bfloat16 h; ushort u; } c; c.h = h; return c.u;
}
__device__ inline float bf2f(ushort u) {
    union { unsigned int i; float f; } c; c.i = ((unsigned int)u) << 16; return c.f;
}
__device__ inline short2 bsplit(float f) {
    ushort hu = f2bf(f);
    short2 r;
    r.x = (short)hu;
    r.y = (short)f2bf(f - bf2f(hu));
    return r;
}

// ---------------------------------------------------------------------------
// k_all: ONE kernel, grid 512 = 256 proj blocks + 256 gram blocks.
// Proj (bid<256, = b x l-tile): r11 k_proj body verbatim. Ends with
//   __threadfence() + atomicAdd(UP[b]) — device-scope release.
// Gram (bid>=256, = b x {term,dq,eo}): spins on UP[b]==8 (agent-scope
//   acquire load), then r11 k_gram body verbatim.
// Deadlock-free: 512 blocks all fit (LDS 65K*2=130<=160K, 8 waves/CU,
//   VGPR<=256); even if every gram block grabs a slot first, 256 slots
//   remain for all proj blocks.
// Counters zeroed per call by a 2KB hipMemsetAsync node (graph-capturable).
// ---------------------------------------------------------------------------
__global__ __launch_bounds__(256) void k_all(
    const float* __restrict__ xr, const float* __restrict__ xi,
    const float* __restrict__ Wr1, const float* __restrict__ br1,
    const float* __restrict__ Wi1, const float* __restrict__ bi1,
    const float* __restrict__ Wr2, const float* __restrict__ br2,
    const float* __restrict__ Wi2, const float* __restrict__ bi2,
    int* __restrict__ cnt, ushort* __restrict__ gtb, float* __restrict__ lgG,
    float* __restrict__ out)
{
    extern __shared__ char L[];

    const int bid   = blockIdx.x;
    const int t     = threadIdx.x;
    const int w     = t >> 6;
    const int lane  = t & 63;
    const int l15   = lane & 15;
    const int koff8 = (lane >> 4) * 8;
    const int koffb = koff8 * 2;

    if (bid < 256) {
        // ================= PROJ =================
        float* lgpart = (float*)L;            // [2 c][4 wave][16 row]
        const int b     = bid >> 3;
        const int lt    = bid & 7;
        const int arowg = b * NL + lt * 16 + l15;

        // A-fragments: X fp32 -> in-reg split
        bf16x8 axh[2][4], axl[2][4];
        {
            const float* xs[2] = {xr, xi};
#pragma unroll
            for (int arr = 0; arr < 2; ++arr)
#pragma unroll
                for (int ks = 0; ks < 4; ++ks) {
                    const float* p = xs[arr] + (size_t)arowg * ND + ks * 32 + koff8;
                    F4 f0, f1;
                    f0.v = *(const float4*)&p[0];
                    f1.v = *(const float4*)&p[4];
                    bf16x8 h, l;
#pragma unroll
                    for (int e = 0; e < 4; ++e) {
                        short2 s = bsplit(f0.f[e]); h[e] = s.x; l[e] = s.y;
                    }
#pragma unroll
                    for (int e = 0; e < 4; ++e) {
                        short2 s = bsplit(f1.f[e]); h[4 + e] = s.x; l[4 + e] = s.y;
                    }
                    axh[arr][ks] = h;
                    axl[arr][ks] = l;
                }
        }

        // proj MFMA: B-frags straight from W fp32 (L2) + in-reg split
        f32x4 acc[4][2];
#pragma unroll
        for (int m = 0; m < 4; ++m)
#pragma unroll
            for (int n = 0; n < 2; ++n) acc[m][n] = (f32x4){0.f, 0.f, 0.f, 0.f};

        {
            const float* Ws[4] = {Wr1, Wi1, Wr2, Wi2};
#pragma unroll
            for (int mat = 0; mat < 4; ++mat) {
                const int arr = mat & 1;
#pragma unroll
                for (int n = 0; n < 2; ++n) {
                    const float* wrow = Ws[mat] + (size_t)((w * 2 + n) * 16 + l15) * ND;
#pragma unroll
                    for (int ks = 0; ks < 4; ++ks) {
                        F4 f0, f1;
                        f0.v = *(const float4*)&wrow[ks * 32 + koff8];
                        f1.v = *(const float4*)&wrow[ks * 32 + koff8 + 4];
                        bf16x8 bh, bl;
#pragma unroll
                        for (int e = 0; e < 4; ++e) {
                            short2 s = bsplit(f0.f[e]); bh[e] = s.x; bl[e] = s.y;
                        }
#pragma unroll
                        for (int e = 0; e < 4; ++e) {
                            short2 s = bsplit(f1.f[e]); bh[4 + e] = s.x; bl[4 + e] = s.y;
                        }
                        acc[mat][n] = __builtin_amdgcn_mfma_f32_16x16x32_bf16(axh[arr][ks], bh, acc[mat][n], 0, 0, 0);
                        acc[mat][n] = __builtin_amdgcn_mfma_f32_16x16x32_bf16(axh[arr][ks], bl, acc[mat][n], 0, 0, 0);
                        acc[mat][n] = __builtin_amdgcn_mfma_f32_16x16x32_bf16(axl[arr][ks], bh, acc[mat][n], 0, 0, 0);
                    }
                }
            }
        }

        // epilogue: bias, partial logits, G writes
        float pR[4] = {0.f, 0.f, 0.f, 0.f};
        float pI[4] = {0.f, 0.f, 0.f, 0.f};
        const int lbase = lt * 16 + (lane >> 4) * 4;
#pragma unroll
        for (int n = 0; n < 2; ++n) {
            const int d = (w * 2 + n) * 16 + l15;
            const float b0 = br1[d], b1 = bi1[d], b2 = br2[d], b3 = bi2[d];
            ushort g2[4], g3[4];
#pragma unroll
            for (int r = 0; r < 4; ++r) {
                float y0 = acc[0][n][r] + b0;
                float y1 = acc[1][n][r] + b1;
                float y2 = acc[2][n][r] + b2;
                float y3 = acc[3][n][r] + b3;
                pR[r] += (y0 * y0 - y1 * y1) * (y2 * y2 - y3 * y3);
                pI[r] += 4.f * y0 * y1 * y2 * y3;
                g2[r] = f2bf(y2);
                g3[r] = f2bf(y3);
            }
            ushort4 q2 = {g2[0], g2[1], g2[2], g2[3]};
            ushort4 q3 = {g3[0], g3[1], g3[2], g3[3]};
            *(ushort4*)&gtb[((size_t)(0 * NB + b) * ND + d) * NL + lbase] = q2;
            *(ushort4*)&gtb[((size_t)(1 * NB + b) * ND + d) * NL + lbase] = q3;
        }

#pragma unroll
        for (int off = 1; off < 16; off <<= 1)
#pragma unroll
            for (int r = 0; r < 4; ++r) {
                pR[r] += __shfl_xor(pR[r], off);
                pI[r] += __shfl_xor(pI[r], off);
            }
        if (l15 == 0) {
            const int row = (lane >> 4) * 4;
#pragma unroll
            for (int r = 0; r < 4; ++r) {
                lgpart[(0 * 4 + w) * 16 + row + r] = pR[r];
                lgpart[(1 * 4 + w) * 16 + row + r] = pI[r];
            }
        }
        __syncthreads();
        if (t < 32) {
            const int c = t >> 4, row = t & 15;
            float s = lgpart[(c * 4 + 0) * 16 + row] + lgpart[(c * 4 + 1) * 16 + row]
                    + lgpart[(c * 4 + 2) * 16 + row] + lgpart[(c * 4 + 3) * 16 + row];
            lgG[(size_t)(c * NB + b) * NL + lt * 16 + row] = s;
        }

        // release: all stores visible, then signal
        __threadfence();
        __syncthreads();
        if (t == 0) atomicAdd(&cnt[b * 16], 1);
    } else {
        // ================= GRAM =================
        float* wfl  = (float*)(L + 65536);
        float* wred = (float*)(L + 66048);

        const int gb   = bid - 256;
        const int b    = gb >> 3;
        const int sub  = gb & 7;
        const int term = sub >> 2;
        const int dq   = (sub >> 1) & 1;
        const int eo   = sub & 1;

        // acquire: wait for the 8 proj blocks of batch b
        if (t == 0) {
            while (__hip_atomic_load(&cnt[b * 16], __ATOMIC_ACQUIRE,
                                     __HIP_MEMORY_SCOPE_AGENT) < 8) {
                __builtin_amdgcn_s_sleep(8);
            }
        }
        __syncthreads();
        __threadfence();

        // softmax (waves 0,1)
        float sv = 0.f, se = 0.f;
        if (t < 128) {
            sv = lgG[(size_t)(term * NB + b) * NL + t];
            float m = sv;
#pragma unroll
            for (int off = 1; off < 64; off <<= 1) m = fmaxf(m, __shfl_xor(m, off));
            if (lane == 0) wred[w] = m;
        }
        __syncthreads();
        if (t < 128) {
            float m = fmaxf(wred[0], wred[1]);
            se = expf(sv - m);
            float s = se;
#pragma unroll
            for (int off = 1; off < 64; off <<= 1) s += __shfl_xor(s, off);
            if (lane == 0) wred[2 + w] = s;
        }
        __syncthreads();
        if (t < 128) wfl[t] = se / (wred[2] + wred[3]);

        // stage G of batch b (both arrays), swizzled
#pragma unroll
        for (int j = 0; j < 16; ++j) {
            int u    = t + 256 * j;
            int arr  = u >> 11;
            int row  = (u >> 4) & 127;
            int slot = u & 15;
            bf16x8 v = *(const bf16x8*)&gtb[((size_t)(arr * NB + b) * ND + row) * NL + slot * 8];
            *(bf16x8*)(L + arr * 32768 + row * 256 + ((slot * 16) ^ ((row & 7) << 4))) = v;
        }
        __syncthreads();

        // gram MFMA with in-register A-scale
        f32x4 accP[4], accN[4];
#pragma unroll
        for (int nt = 0; nt < 4; ++nt) {
            accP[nt] = (f32x4){0.f, 0.f, 0.f, 0.f};
            accN[nt] = (f32x4){0.f, 0.f, 0.f, 0.f};
        }

#pragma unroll
        for (int ks = 0; ks < 4; ++ks) {
            F4 w0, w1;
            w0.v = *(const float4*)&wfl[ks * 32 + koff8];
            w1.v = *(const float4*)&wfl[ks * 32 + koff8 + 4];
            float wv[8] = {w0.f[0], w0.f[1], w0.f[2], w0.f[3],
                           w1.f[0], w1.f[1], w1.f[2], w1.f[3]};

            const int ar = dq * 64 + w * 16 + l15;
            const int ab = ar * 256 + (((ks * 64) + koffb) ^ ((ar & 7) << 4));
            BF8 a0; a0.v = *(const bf16x8*)(L + ab);
            BF8 a1; a1.v = *(const bf16x8*)(L + 32768 + ab);
            bf16x8 s0, s1;
#pragma unroll
            for (int e = 0; e < 8; ++e) {
                s0[e] = (short)f2bf(bf2f(a0.u[e]) * wv[e]);
                s1[e] = (short)f2bf(bf2f(a1.u[e]) * wv[e]);
            }
            bf16x8 aP = term ? s1 : s0;   // R: wr.r2 ; I: wi.i2
            bf16x8 aN = term ? s0 : s1;   // R: wr.i2 ; I: wi.r2

#pragma unroll
            for (int nt = 0; nt < 4; ++nt) {
                const int br = eo * 64 + nt * 16 + l15;
                const int bb = br * 256 + (((ks * 64) + koffb) ^ ((br & 7) << 4));
                bf16x8 b0 = *(const bf16x8*)(L + bb);
                bf16x8 b1 = *(const bf16x8*)(L + 32768 + bb);
                accP[nt] = __builtin_amdgcn_mfma_f32_16x16x32_bf16(aP, b0, accP[nt], 0, 0, 0);
                accN[nt] = __builtin_amdgcn_mfma_f32_16x16x32_bf16(aN, b1, accN[nt], 0, 0, 0);
            }
        }

        const float sgn = term ? 1.f : -1.f;
        float* dst = out + (size_t)term * NB * ND * ND + (size_t)b * ND * ND;
        const int rb = dq * 64 + w * 16 + (lane >> 4) * 4;
#pragma unroll
        for (int nt = 0; nt < 4; ++nt) {
            const int ec = eo * 64 + nt * 16 + l15;
#pragma unroll
            for (int r = 0; r < 4; ++r)
                dst[(size_t)(rb + r) * ND + ec] = accP[nt][r] + sgn * accN[nt][r];
        }
    }
}

extern "C" void kernel_launch(void* const* d_in, const int* in_sizes, int n_in,
                              void* d_out, int out_size, void* d_ws, size_t ws_size,
                              hipStream_t stream)
{
    const float* xr  = (const float*)d_in[0];
    const float* xi  = (const float*)d_in[1];
    const float* Wr1 = (const float*)d_in[2];
    const float* br1 = (const float*)d_in[3];
    const float* Wi1 = (const float*)d_in[4];
    const float* bi1 = (const float*)d_in[5];
    const float* Wr2 = (const float*)d_in[6];
    const float* br2 = (const float*)d_in[7];
    const float* Wi2 = (const float*)d_in[8];
    const float* bi2 = (const float*)d_in[9];

    int*    cnt = (int*)d_ws;                        // 32 counters, 64B apart
    ushort* gtb = (ushort*)((char*)d_ws + 2048);     // [2][b][d][l] bf16
    float*  lgG = (float*)(gtb + 2 * NB * ND * NL);  // [2][b][l]

    (void)hipFuncSetAttribute((const void*)k_all,
                              hipFuncAttributeMaxDynamicSharedMemorySize, 66560);

    hipMemsetAsync(cnt, 0, 2048, stream);
    hipLaunchKernelGGL(k_all, dim3(512), dim3(256), 66560, stream,
                       xr, xi, Wr1, br1, Wi1, bi1, Wr2, br2, Wi2, bi2,
                       cnt, gtb, lgG, (float*)d_out);
}

// Round 13
// 70.501 us; speedup vs baseline: 1.4033x; 1.4033x over previous
//
#include <hip/hip_runtime.h>
#include <hip/hip_bf16.h>
#include <math.h>

#define NB 32
#define NL 128
#define ND 128

typedef __attribute__((ext_vector_type(8))) short bf16x8;
typedef __attribute__((ext_vector_type(4))) float f32x4;

union F4  { float4 v; float f[4]; };
union BF8 { bf16x8 v; ushort u[8]; };

__device__ inline ushort f2bf(float f) {
    __hip_bfloat16 h = __float2bfloat16(f);
    union { __hip_bfloat16 h; ushort u; } c; c.h = h; return c.u;
}
__device__ inline float bf2f(ushort u) {
    union { unsigned int i; float f; } c; c.i = ((unsigned int)u) << 16; return c.f;
}
__device__ inline short2 bsplit(float f) {
    ushort hu = f2bf(f);
    short2 r;
    r.x = (short)hu;
    r.y = (short)f2bf(f - bf2f(hu));
    return r;
}

// ---------------------------------------------------------------------------
// k_one: ONE data-parallel kernel, grid 256 = b(32) x {term,dq,eo}(8),
// block 256 (4 waves). ZERO cross-block dependencies — each block
// redundantly computes the full batch-b pipeline (lesson r10/r12: any
// cross-block wait costs ~100us on MI355X; redundant compute is cheaper).
//
// Proj: wave w owns l-tiles {w, w+4}; loops nt=0..7 (full d). W-fragments
//   loaded once per (mat,nt,ks) from global fp32 (L1/L2-hot; in-reg bsplit,
//   r6-verified split-bf16 MFMA XhWh+XhWl+XlWh), shared by both l-tiles.
//   acc[4 mats][2 lt]. Epilogue per nt: bias, logit partials, y2/y3 bf16
//   -> G in LDS (r8-verified swizzled [arr][d][l] layout, direct produce).
// Logits: full-d per wave -> single 16-lane shfl reduce -> lgs (LDS).
// Softmax: block's term only, waves 0-1 (r11-verified pattern).
// Gram: r11 body verbatim minus the staging loop (G already in LDS).
//   Mr = (wr.r2)r2^T - (wr.i2)i2^T ; Mi = (wi.i2)r2^T + (wi.r2)i2^T.
// LDS: G 64K @0, lgs 1K @65536, wfl 512B @66560, wred @67072 (~66 KB).
// ---------------------------------------------------------------------------
__global__ __launch_bounds__(256, 1) void k_one(
    const float* __restrict__ xr, const float* __restrict__ xi,
    const float* __restrict__ Wr1, const float* __restrict__ br1,
    const float* __restrict__ Wi1, const float* __restrict__ bi1,
    const float* __restrict__ Wr2, const float* __restrict__ br2,
    const float* __restrict__ Wi2, const float* __restrict__ bi2,
    float* __restrict__ out)
{
    extern __shared__ char L[];
    float* lgs  = (float*)(L + 65536);   // [2 c][128 l]
    float* wfl  = (float*)(L + 66560);   // [128]
    float* wred = (float*)(L + 67072);   // 4 floats

    const int t     = threadIdx.x;
    const int w     = t >> 6;
    const int lane  = t & 63;
    const int l15   = lane & 15;
    const int koff8 = (lane >> 4) * 8;
    const int koffb = koff8 * 2;

    const int bid  = blockIdx.x;
    const int b    = bid >> 3;
    const int sub  = bid & 7;
    const int term = sub >> 2;
    const int dq   = (sub >> 1) & 1;
    const int eo   = sub & 1;

    // ---- A-fragments: X fp32 -> in-reg split, both l-tiles {w, w+4} ----
    bf16x8 axh[2][2][4], axl[2][2][4];   // [lt2][arr][ks]
    {
        const float* xs[2] = {xr, xi};
#pragma unroll
        for (int lt2 = 0; lt2 < 2; ++lt2) {
            const int arowg = b * NL + (w + 4 * lt2) * 16 + l15;
#pragma unroll
            for (int arr = 0; arr < 2; ++arr)
#pragma unroll
                for (int ks = 0; ks < 4; ++ks) {
                    const float* p = xs[arr] + (size_t)arowg * ND + ks * 32 + koff8;
                    F4 f0, f1;
                    f0.v = *(const float4*)&p[0];
                    f1.v = *(const float4*)&p[4];
                    bf16x8 h, l;
#pragma unroll
                    for (int e = 0; e < 4; ++e) {
                        short2 s = bsplit(f0.f[e]); h[e] = s.x; l[e] = s.y;
                    }
#pragma unroll
                    for (int e = 0; e < 4; ++e) {
                        short2 s = bsplit(f1.f[e]); h[4 + e] = s.x; l[4 + e] = s.y;
                    }
                    axh[lt2][arr][ks] = h;
                    axl[lt2][arr][ks] = l;
                }
        }
    }

    // ---- proj over all 8 nt (full d): W-frags shared across both lt ----
    float pR[2][4] = {{0.f,0.f,0.f,0.f},{0.f,0.f,0.f,0.f}};
    float pI[2][4] = {{0.f,0.f,0.f,0.f},{0.f,0.f,0.f,0.f}};
    {
        const float* Ws[4] = {Wr1, Wi1, Wr2, Wi2};
#pragma unroll
        for (int nt = 0; nt < 8; ++nt) {
            f32x4 acc[4][2];
#pragma unroll
            for (int m = 0; m < 4; ++m)
#pragma unroll
                for (int lt2 = 0; lt2 < 2; ++lt2)
                    acc[m][lt2] = (f32x4){0.f, 0.f, 0.f, 0.f};

#pragma unroll
            for (int mat = 0; mat < 4; ++mat) {
                const int arr = mat & 1;
                const float* wrow = Ws[mat] + (size_t)(nt * 16 + l15) * ND;
#pragma unroll
                for (int ks = 0; ks < 4; ++ks) {
                    F4 f0, f1;
                    f0.v = *(const float4*)&wrow[ks * 32 + koff8];
                    f1.v = *(const float4*)&wrow[ks * 32 + koff8 + 4];
                    bf16x8 bh, bl;
#pragma unroll
                    for (int e = 0; e < 4; ++e) {
                        short2 s = bsplit(f0.f[e]); bh[e] = s.x; bl[e] = s.y;
                    }
#pragma unroll
                    for (int e = 0; e < 4; ++e) {
                        short2 s = bsplit(f1.f[e]); bh[4 + e] = s.x; bl[4 + e] = s.y;
                    }
                    acc[mat][0] = __builtin_amdgcn_mfma_f32_16x16x32_bf16(axh[0][arr][ks], bh, acc[mat][0], 0, 0, 0);
                    acc[mat][0] = __builtin_amdgcn_mfma_f32_16x16x32_bf16(axh[0][arr][ks], bl, acc[mat][0], 0, 0, 0);
                    acc[mat][0] = __builtin_amdgcn_mfma_f32_16x16x32_bf16(axl[0][arr][ks], bh, acc[mat][0], 0, 0, 0);
                    acc[mat][1] = __builtin_amdgcn_mfma_f32_16x16x32_bf16(axh[1][arr][ks], bh, acc[mat][1], 0, 0, 0);
                    acc[mat][1] = __builtin_amdgcn_mfma_f32_16x16x32_bf16(axh[1][arr][ks], bl, acc[mat][1], 0, 0, 0);
                    acc[mat][1] = __builtin_amdgcn_mfma_f32_16x16x32_bf16(axl[1][arr][ks], bh, acc[mat][1], 0, 0, 0);
                }
            }

            // epilogue for this nt: bias, logit partials, G -> LDS
            const int d  = nt * 16 + l15;
            const float b0 = br1[d], b1 = bi1[d], b2 = br2[d], b3 = bi2[d];
#pragma unroll
            for (int lt2 = 0; lt2 < 2; ++lt2) {
                const int lb = (w + 4 * lt2) * 16 + (lane >> 4) * 4;
                ushort g2[4], g3[4];
#pragma unroll
                for (int r = 0; r < 4; ++r) {
                    float y0 = acc[0][lt2][r] + b0;
                    float y1 = acc[1][lt2][r] + b1;
                    float y2 = acc[2][lt2][r] + b2;
                    float y3 = acc[3][lt2][r] + b3;
                    pR[lt2][r] += (y0 * y0 - y1 * y1) * (y2 * y2 - y3 * y3);
                    pI[lt2][r] += 4.f * y0 * y1 * y2 * y3;
                    g2[r] = f2bf(y2);
                    g3[r] = f2bf(y3);
                }
                const int byte0 = d * 256 + ((lb * 2) ^ ((d & 7) << 4));
                *(unsigned int*)(L + byte0)             = (unsigned int)g2[0] | ((unsigned int)g2[1] << 16);
                *(unsigned int*)(L + byte0 + 4)         = (unsigned int)g2[2] | ((unsigned int)g2[3] << 16);
                *(unsigned int*)(L + 32768 + byte0)     = (unsigned int)g3[0] | ((unsigned int)g3[1] << 16);
                *(unsigned int*)(L + 32768 + byte0 + 4) = (unsigned int)g3[2] | ((unsigned int)g3[3] << 16);
            }
        }
    }

    // ---- logits: full-d per wave -> 16-lane shfl reduce -> lgs ----
#pragma unroll
    for (int off = 1; off < 16; off <<= 1)
#pragma unroll
        for (int lt2 = 0; lt2 < 2; ++lt2)
#pragma unroll
            for (int r = 0; r < 4; ++r) {
                pR[lt2][r] += __shfl_xor(pR[lt2][r], off);
                pI[lt2][r] += __shfl_xor(pI[lt2][r], off);
            }
    if (l15 == 0) {
#pragma unroll
        for (int lt2 = 0; lt2 < 2; ++lt2) {
            const int row = (w + 4 * lt2) * 16 + (lane >> 4) * 4;
#pragma unroll
            for (int r = 0; r < 4; ++r) {
                lgs[row + r]       = pR[lt2][r];
                lgs[128 + row + r] = pI[lt2][r];
            }
        }
    }
    __syncthreads();   // G writes + lgs visible block-wide

    // ---- softmax for this block's term (waves 0,1) ----
    float sv = 0.f, se = 0.f;
    if (t < 128) {
        sv = lgs[term * 128 + t];
        float m = sv;
#pragma unroll
        for (int off = 1; off < 64; off <<= 1) m = fmaxf(m, __shfl_xor(m, off));
        if (lane == 0) wred[w] = m;
    }
    __syncthreads();
    if (t < 128) {
        float m = fmaxf(wred[0], wred[1]);
        se = expf(sv - m);
        float s = se;
#pragma unroll
        for (int off = 1; off < 64; off <<= 1) s += __shfl_xor(s, off);
        if (lane == 0) wred[2 + w] = s;
    }
    __syncthreads();
    if (t < 128) wfl[t] = se / (wred[2] + wred[3]);
    __syncthreads();

    // ---- gram MFMA with in-register A-scale (r11-verified; G resident) ----
    f32x4 accP[4], accN[4];
#pragma unroll
    for (int nt = 0; nt < 4; ++nt) {
        accP[nt] = (f32x4){0.f, 0.f, 0.f, 0.f};
        accN[nt] = (f32x4){0.f, 0.f, 0.f, 0.f};
    }

#pragma unroll
    for (int ks = 0; ks < 4; ++ks) {
        F4 w0, w1;
        w0.v = *(const float4*)&wfl[ks * 32 + koff8];
        w1.v = *(const float4*)&wfl[ks * 32 + koff8 + 4];
        float wv[8] = {w0.f[0], w0.f[1], w0.f[2], w0.f[3],
                       w1.f[0], w1.f[1], w1.f[2], w1.f[3]};

        const int ar = dq * 64 + w * 16 + l15;
        const int ab = ar * 256 + (((ks * 64) + koffb) ^ ((ar & 7) << 4));
        BF8 a0; a0.v = *(const bf16x8*)(L + ab);
        BF8 a1; a1.v = *(const bf16x8*)(L + 32768 + ab);
        bf16x8 s0, s1;
#pragma unroll
        for (int e = 0; e < 8; ++e) {
            s0[e] = (short)f2bf(bf2f(a0.u[e]) * wv[e]);
            s1[e] = (short)f2bf(bf2f(a1.u[e]) * wv[e]);
        }
        bf16x8 aP = term ? s1 : s0;   // R: wr.r2 ; I: wi.i2
        bf16x8 aN = term ? s0 : s1;   // R: wr.i2 ; I: wi.r2

#pragma unroll
        for (int nt = 0; nt < 4; ++nt) {
            const int br = eo * 64 + nt * 16 + l15;
            const int bb = br * 256 + (((ks * 64) + koffb) ^ ((br & 7) << 4));
            bf16x8 b0 = *(const bf16x8*)(L + bb);
            bf16x8 b1 = *(const bf16x8*)(L + 32768 + bb);
            accP[nt] = __builtin_amdgcn_mfma_f32_16x16x32_bf16(aP, b0, accP[nt], 0, 0, 0);
            accN[nt] = __builtin_amdgcn_mfma_f32_16x16x32_bf16(aN, b1, accN[nt], 0, 0, 0);
        }
    }

    const float sgn = term ? 1.f : -1.f;
    float* dst = out + (size_t)term * NB * ND * ND + (size_t)b * ND * ND;
    const int rb = dq * 64 + w * 16 + (lane >> 4) * 4;
#pragma unroll
    for (int nt = 0; nt < 4; ++nt) {
        const int ec = eo * 64 + nt * 16 + l15;
#pragma unroll
        for (int r = 0; r < 4; ++r)
            dst[(size_t)(rb + r) * ND + ec] = accP[nt][r] + sgn * accN[nt][r];
    }
}

extern "C" void kernel_launch(void* const* d_in, const int* in_sizes, int n_in,
                              void* d_out, int out_size, void* d_ws, size_t ws_size,
                              hipStream_t stream)
{
    const float* xr  = (const float*)d_in[0];
    const float* xi  = (const float*)d_in[1];
    const float* Wr1 = (const float*)d_in[2];
    const float* br1 = (const float*)d_in[3];
    const float* Wi1 = (const float*)d_in[4];
    const float* bi1 = (const float*)d_in[5];
    const float* Wr2 = (const float*)d_in[6];
    const float* br2 = (const float*)d_in[7];
    const float* Wi2 = (const float*)d_in[8];
    const float* bi2 = (const float*)d_in[9];

    (void)hipFuncSetAttribute((const void*)k_one,
                              hipFuncAttributeMaxDynamicSharedMemorySize, 67584);

    hipLaunchKernelGGL(k_one, dim3(256), dim3(256), 67584, stream,
                       xr, xi, Wr1, br1, Wi1, bi1, Wr2, br2, Wi2, bi2,
                       (float*)d_out);
}

// Round 14
// 29.686 us; speedup vs baseline: 3.3326x; 2.3749x over previous
//
#include <hip/hip_runtime.h>
#include <hip/hip_bf16.h>
#include <math.h>

#define NB 32
#define NL 128
#define ND 128

typedef __attribute__((ext_vector_type(8))) short bf16x8;
typedef __attribute__((ext_vector_type(4))) float f32x4;

union F4  { float4 v; float f[4]; };
union BF8 { bf16x8 v; ushort u[8]; };

__device__ inline ushort f2bf(float f) {
    __hip_bfloat16 h = __float2bfloat16(f);
    union { __hip_bfloat16 h; ushort u; } c; c.h = h; return c.u;
}
__device__ inline float bf2f(ushort u) {
    union { unsigned int i; float f; } c; c.i = ((unsigned int)u) << 16; return c.f;
}
__device__ inline short2 bsplit(float f) {
    ushort hu = f2bf(f);
    short2 r;
    r.x = (short)hu;
    r.y = (short)f2bf(f - bf2f(hu));
    return r;
}

// ---------------------------------------------------------------------------
// k_one: ONE data-parallel kernel, grid 256 = b(32) x {term,dq,eo}(8),
// block 256 (4 waves), 1 block/CU. Zero cross-block deps (r10/r12 lesson).
// r13's redundant-proj plan, with the diagnosed L2-latency failure fixed:
// W is staged through a double-buffered LDS pipeline (m97 pattern: next
// tile's global loads issued BEFORE this tile's MFMA, LDS write after ->
// latency hides under compute; 2 barriers/step).
//
// Per nt-step (8 steps): stage W-tile = all 4 mats x 16 d-rows x 128 k
//   (fp32 -> bf16 hi/lo in-reg, 32 KB buffer x2). Wave w owns l-tiles
//   {w, w+4}; W-frags from LDS (verified zero-conflict b128 pattern),
//   shared across both l-tiles. Split-bf16 MFMA XhWh+XhWl+XlWh
//   (r6-verified). Epilogue per nt: bias, logit partials, y2/y3 bf16 ->
//   G in LDS (r8-verified swizzled [arr][d][l]).
// Logits -> lgs (r13-verified), softmax (r11-verified), gram from
//   resident G with in-register A-scale (r11/r13-verified).
// LDS: G 64K @0, Wbuf 2x32K @65536, lgs @131072, wfl @132096, wred @132608.
// ---------------------------------------------------------------------------
__global__ __launch_bounds__(256, 1) void k_one(
    const float* __restrict__ xr, const float* __restrict__ xi,
    const float* __restrict__ Wr1, const float* __restrict__ br1,
    const float* __restrict__ Wi1, const float* __restrict__ bi1,
    const float* __restrict__ Wr2, const float* __restrict__ br2,
    const float* __restrict__ Wi2, const float* __restrict__ bi2,
    float* __restrict__ out)
{
    extern __shared__ char L[];
    char*  Wb   = L + 65536;             // 2 bufs x 32768: [mat][hl][row][256B]
    float* lgs  = (float*)(L + 131072);  // [2 c][128 l]
    float* wfl  = (float*)(L + 132096);  // [128]
    float* wred = (float*)(L + 132608);  // 4 floats

    const int t     = threadIdx.x;
    const int w     = t >> 6;
    const int lane  = t & 63;
    const int l15   = lane & 15;
    const int koff8 = (lane >> 4) * 8;
    const int koffb = koff8 * 2;

    const int bid  = blockIdx.x;
    const int b    = bid >> 3;
    const int sub  = bid & 7;
    const int term = sub >> 2;
    const int dq   = (sub >> 1) & 1;
    const int eo   = sub & 1;

    // staging role: wave = mat, rows (t>>2)&15, 4 threads per 128-float row
    const int srow = (t >> 2) & 15;
    const float* Wsrc = (w == 0) ? Wr1 : (w == 1) ? Wi1 : (w == 2) ? Wr2 : Wi2;

    F4 wpf[8];   // W prefetch: 8 float4 per thread (one tile-slice)

#define LOADW(NT)                                                             \
    {                                                                         \
        const float* p = Wsrc + (size_t)((NT) * 16 + srow) * ND;              \
        _Pragma("unroll")                                                     \
        for (int j = 0; j < 8; ++j)                                           \
            wpf[j].v = *(const float4*)&p[((t & 3) + 4 * j) * 4];             \
    }

#define WRITEW(BUF)                                                           \
    {                                                                         \
        char* mb = Wb + (BUF) * 32768 + w * 8192 + srow * 256;                \
        const int sw = (srow & 7) << 4;                                       \
        _Pragma("unroll")                                                     \
        for (int j = 0; j < 8; ++j) {                                         \
            short2 s0 = bsplit(wpf[j].f[0]), s1 = bsplit(wpf[j].f[1]);        \
            short2 s2 = bsplit(wpf[j].f[2]), s3 = bsplit(wpf[j].f[3]);        \
            int kb = ((t & 3) + 4 * j) * 8;                                   \
            ushort4 hh = {(ushort)s0.x, (ushort)s1.x, (ushort)s2.x, (ushort)s3.x}; \
            ushort4 ll = {(ushort)s0.y, (ushort)s1.y, (ushort)s2.y, (ushort)s3.y}; \
            *(ushort4*)(mb + (kb ^ sw))        = hh;                          \
            *(ushort4*)(mb + 4096 + (kb ^ sw)) = ll;                          \
        }                                                                     \
    }

    // ---- A-fragments: X fp32 -> in-reg split, l-tiles {w, w+4} ----
    bf16x8 axh[2][2][4], axl[2][2][4];   // [lt2][arr][ks]
    {
        const float* xs[2] = {xr, xi};
#pragma unroll
        for (int lt2 = 0; lt2 < 2; ++lt2) {
            const int arowg = b * NL + (w + 4 * lt2) * 16 + l15;
#pragma unroll
            for (int arr = 0; arr < 2; ++arr)
#pragma unroll
                for (int ks = 0; ks < 4; ++ks) {
                    const float* p = xs[arr] + (size_t)arowg * ND + ks * 32 + koff8;
                    F4 f0, f1;
                    f0.v = *(const float4*)&p[0];
                    f1.v = *(const float4*)&p[4];
                    bf16x8 h, l;
#pragma unroll
                    for (int e = 0; e < 4; ++e) {
                        short2 s = bsplit(f0.f[e]); h[e] = s.x; l[e] = s.y;
                    }
#pragma unroll
                    for (int e = 0; e < 4; ++e) {
                        short2 s = bsplit(f1.f[e]); h[4 + e] = s.x; l[4 + e] = s.y;
                    }
                    axh[lt2][arr][ks] = h;
                    axl[lt2][arr][ks] = l;
                }
        }
    }

    float pR[2][4] = {{0.f,0.f,0.f,0.f},{0.f,0.f,0.f,0.f}};
    float pI[2][4] = {{0.f,0.f,0.f,0.f},{0.f,0.f,0.f,0.f}};

    // ---- proj pipeline: 8 nt-steps, W double-buffered through LDS ----
    LOADW(0)
    WRITEW(0)
    __syncthreads();

    for (int nt = 0; nt < 8; ++nt) {
        if (nt < 7) LOADW(nt + 1)        // issue next tile's loads NOW

        // compute step nt from buf nt&1
        f32x4 acc[4][2];
#pragma unroll
        for (int m = 0; m < 4; ++m)
#pragma unroll
            for (int lt2 = 0; lt2 < 2; ++lt2)
                acc[m][lt2] = (f32x4){0.f, 0.f, 0.f, 0.f};

        {
            const char* bufp = Wb + (nt & 1) * 32768 + l15 * 256;
            const int swr = (l15 & 7) << 4;
#pragma unroll
            for (int mat = 0; mat < 4; ++mat) {
                const int arr = mat & 1;
                const char* mb = bufp + mat * 8192;
#pragma unroll
                for (int ks = 0; ks < 4; ++ks) {
                    const int off = ((ks * 64) + koffb) ^ swr;
                    bf16x8 bh = *(const bf16x8*)(mb + off);
                    bf16x8 bl = *(const bf16x8*)(mb + 4096 + off);
                    acc[mat][0] = __builtin_amdgcn_mfma_f32_16x16x32_bf16(axh[0][arr][ks], bh, acc[mat][0], 0, 0, 0);
                    acc[mat][0] = __builtin_amdgcn_mfma_f32_16x16x32_bf16(axh[0][arr][ks], bl, acc[mat][0], 0, 0, 0);
                    acc[mat][0] = __builtin_amdgcn_mfma_f32_16x16x32_bf16(axl[0][arr][ks], bh, acc[mat][0], 0, 0, 0);
                    acc[mat][1] = __builtin_amdgcn_mfma_f32_16x16x32_bf16(axh[1][arr][ks], bh, acc[mat][1], 0, 0, 0);
                    acc[mat][1] = __builtin_amdgcn_mfma_f32_16x16x32_bf16(axh[1][arr][ks], bl, acc[mat][1], 0, 0, 0);
                    acc[mat][1] = __builtin_amdgcn_mfma_f32_16x16x32_bf16(axl[1][arr][ks], bh, acc[mat][1], 0, 0, 0);
                }
            }
        }

        // epilogue for this nt: bias, logit partials, G -> LDS
        {
            const int d  = nt * 16 + l15;
            const float b0 = br1[d], b1 = bi1[d], b2 = br2[d], b3 = bi2[d];
#pragma unroll
            for (int lt2 = 0; lt2 < 2; ++lt2) {
                const int lb = (w + 4 * lt2) * 16 + (lane >> 4) * 4;
                ushort g2[4], g3[4];
#pragma unroll
                for (int r = 0; r < 4; ++r) {
                    float y0 = acc[0][lt2][r] + b0;
                    float y1 = acc[1][lt2][r] + b1;
                    float y2 = acc[2][lt2][r] + b2;
                    float y3 = acc[3][lt2][r] + b3;
                    pR[lt2][r] += (y0 * y0 - y1 * y1) * (y2 * y2 - y3 * y3);
                    pI[lt2][r] += 4.f * y0 * y1 * y2 * y3;
                    g2[r] = f2bf(y2);
                    g3[r] = f2bf(y3);
                }
                const int byte0 = d * 256 + ((lb * 2) ^ ((d & 7) << 4));
                *(unsigned int*)(L + byte0)             = (unsigned int)g2[0] | ((unsigned int)g2[1] << 16);
                *(unsigned int*)(L + byte0 + 4)         = (unsigned int)g2[2] | ((unsigned int)g2[3] << 16);
                *(unsigned int*)(L + 32768 + byte0)     = (unsigned int)g3[0] | ((unsigned int)g3[1] << 16);
                *(unsigned int*)(L + 32768 + byte0 + 4) = (unsigned int)g3[2] | ((unsigned int)g3[3] << 16);
            }
        }

        __syncthreads();                 // buf[nt&1] reads done
        if (nt < 7) {
            WRITEW((nt + 1) & 1)         // write next tile (other buffer)
            __syncthreads();
        }
    }

    // ---- logits: full-d per wave -> 16-lane shfl reduce -> lgs ----
#pragma unroll
    for (int off = 1; off < 16; off <<= 1)
#pragma unroll
        for (int lt2 = 0; lt2 < 2; ++lt2)
#pragma unroll
            for (int r = 0; r < 4; ++r) {
                pR[lt2][r] += __shfl_xor(pR[lt2][r], off);
                pI[lt2][r] += __shfl_xor(pI[lt2][r], off);
            }
    if (l15 == 0) {
#pragma unroll
        for (int lt2 = 0; lt2 < 2; ++lt2) {
            const int row = (w + 4 * lt2) * 16 + (lane >> 4) * 4;
#pragma unroll
            for (int r = 0; r < 4; ++r) {
                lgs[row + r]       = pR[lt2][r];
                lgs[128 + row + r] = pI[lt2][r];
            }
        }
    }
    __syncthreads();   // G + lgs visible block-wide

    // ---- softmax for this block's term (waves 0,1) ----
    float sv = 0.f, se = 0.f;
    if (t < 128) {
        sv = lgs[term * 128 + t];
        float m = sv;
#pragma unroll
        for (int off = 1; off < 64; off <<= 1) m = fmaxf(m, __shfl_xor(m, off));
        if (lane == 0) wred[w] = m;
    }
    __syncthreads();
    if (t < 128) {
        float m = fmaxf(wred[0], wred[1]);
        se = expf(sv - m);
        float s = se;
#pragma unroll
        for (int off = 1; off < 64; off <<= 1) s += __shfl_xor(s, off);
        if (lane == 0) wred[2 + w] = s;
    }
    __syncthreads();
    if (t < 128) wfl[t] = se / (wred[2] + wred[3]);
    __syncthreads();

    // ---- gram MFMA with in-register A-scale (G resident in LDS) ----
    f32x4 accP[4], accN[4];
#pragma unroll
    for (int nt = 0; nt < 4; ++nt) {
        accP[nt] = (f32x4){0.f, 0.f, 0.f, 0.f};
        accN[nt] = (f32x4){0.f, 0.f, 0.f, 0.f};
    }

#pragma unroll
    for (int ks = 0; ks < 4; ++ks) {
        F4 w0, w1;
        w0.v = *(const float4*)&wfl[ks * 32 + koff8];
        w1.v = *(const float4*)&wfl[ks * 32 + koff8 + 4];
        float wv[8] = {w0.f[0], w0.f[1], w0.f[2], w0.f[3],
                       w1.f[0], w1.f[1], w1.f[2], w1.f[3]};

        const int ar = dq * 64 + w * 16 + l15;
        const int ab = ar * 256 + (((ks * 64) + koffb) ^ ((ar & 7) << 4));
        BF8 a0; a0.v = *(const bf16x8*)(L + ab);
        BF8 a1; a1.v = *(const bf16x8*)(L + 32768 + ab);
        bf16x8 s0, s1;
#pragma unroll
        for (int e = 0; e < 8; ++e) {
            s0[e] = (short)f2bf(bf2f(a0.u[e]) * wv[e]);
            s1[e] = (short)f2bf(bf2f(a1.u[e]) * wv[e]);
        }
        bf16x8 aP = term ? s1 : s0;   // R: wr.r2 ; I: wi.i2
        bf16x8 aN = term ? s0 : s1;   // R: wr.i2 ; I: wi.r2

#pragma unroll
        for (int nt = 0; nt < 4; ++nt) {
            const int br = eo * 64 + nt * 16 + l15;
            const int bb = br * 256 + (((ks * 64) + koffb) ^ ((br & 7) << 4));
            bf16x8 b0 = *(const bf16x8*)(L + bb);
            bf16x8 b1 = *(const bf16x8*)(L + 32768 + bb);
            accP[nt] = __builtin_amdgcn_mfma_f32_16x16x32_bf16(aP, b0, accP[nt], 0, 0, 0);
            accN[nt] = __builtin_amdgcn_mfma_f32_16x16x32_bf16(aN, b1, accN[nt], 0, 0, 0);
        }
    }

    const float sgn = term ? 1.f : -1.f;
    float* dst = out + (size_t)term * NB * ND * ND + (size_t)b * ND * ND;
    const int rb = dq * 64 + w * 16 + (lane >> 4) * 4;
#pragma unroll
    for (int nt = 0; nt < 4; ++nt) {
        const int ec = eo * 64 + nt * 16 + l15;
#pragma unroll
        for (int r = 0; r < 4; ++r)
            dst[(size_t)(rb + r) * ND + ec] = accP[nt][r] + sgn * accN[nt][r];
    }
}

extern "C" void kernel_launch(void* const* d_in, const int* in_sizes, int n_in,
                              void* d_out, int out_size, void* d_ws, size_t ws_size,
                              hipStream_t stream)
{
    const float* xr  = (const float*)d_in[0];
    const float* xi  = (const float*)d_in[1];
    const float* Wr1 = (const float*)d_in[2];
    const float* br1 = (const float*)d_in[3];
    const float* Wi1 = (const float*)d_in[4];
    const float* bi1 = (const float*)d_in[5];
    const float* Wr2 = (const float*)d_in[6];
    const float* br2 = (const float*)d_in[7];
    const float* Wi2 = (const float*)d_in[8];
    const float* bi2 = (const float*)d_in[9];

    (void)hipFuncSetAttribute((const void*)k_one,
                              hipFuncAttributeMaxDynamicSharedMemorySize, 132672);

    hipLaunchKernelGGL(k_one, dim3(256), dim3(256), 132672, stream,
                       xr, xi, Wr1, br1, Wi1, bi1, Wr2, br2, Wi2, bi2,
                       (float*)d_out);
}

// Round 15
// 25.855 us; speedup vs baseline: 3.8263x; 1.1481x over previous
//
#include <hip/hip_runtime.h>
#include <hip/hip_bf16.h>
#include <math.h>

#define NB 32
#define NL 128
#define ND 128

typedef __attribute__((ext_vector_type(8))) short bf16x8;
typedef __attribute__((ext_vector_type(4))) float f32x4;

union F4  { float4 v; float f[4]; };
union BF8 { bf16x8 v; ushort u[8]; };

__device__ inline ushort f2bf(float f) {
    __hip_bfloat16 h = __float2bfloat16(f);
    union { __hip_bfloat16 h; ushort u; } c; c.h = h; return c.u;
}
__device__ inline float bf2f(ushort u) {
    union { unsigned int i; float f; } c; c.i = ((unsigned int)u) << 16; return c.f;
}
__device__ inline short2 bsplit(float f) {
    ushort hu = f2bf(f);
    short2 r;
    r.x = (short)hu;
    r.y = (short)f2bf(f - bf2f(hu));
    return r;
}

// ---------------------------------------------------------------------------
// k_one: ONE data-parallel kernel, grid 256 = b(32) x {term,dq,eo}(8),
// block 512 = 8 waves (2 waves/SIMD — the r14 fix: r14's 4-wave version
// left every latency exposed at 1 wave/SIMD). Zero cross-block deps.
//
// Proj (redundant full-batch per block): wave w owns l-tile w (16 rows).
//   8 nt-steps, W double-buffered through LDS, ONE barrier per step
//   (write-next-buf vs compute-current-buf touch different buffers).
//   W staged by all 512 threads: mat=t>>7, row=(t>>3)&15, kq=t&7 ->
//   4 float4 loads + 16 bsplits/thread/step. Split-bf16 MFMA
//   XhWh+XhWl+XlWh (r6-verified). Epilogue per nt: bias, logit partials,
//   y2/y3 bf16 -> G in LDS (r8-verified swizzled [arr][d][l]).
// Logits: per-wave full-d -> 16-lane shfl -> lgs (each wave owns its rows).
// Softmax: block's term, waves 0-1 (r11-verified).
// Gram: 8 waves: m-tile = w&3, nt-pair = w>>2; in-register A-scale
//   (r11/r13/r14-verified). Mr=(wr.r2)r2^T-(wr.i2)i2^T; Mi=(wi.i2)r2^T+(wi.r2)i2^T.
// LDS: G 64K @0, Wbuf 2x32K @65536, lgs @131072, wfl @132096, wred @132608.
// ---------------------------------------------------------------------------
__global__ __launch_bounds__(512, 1) void k_one(
    const float* __restrict__ xr, const float* __restrict__ xi,
    const float* __restrict__ Wr1, const float* __restrict__ br1,
    const float* __restrict__ Wi1, const float* __restrict__ bi1,
    const float* __restrict__ Wr2, const float* __restrict__ br2,
    const float* __restrict__ Wi2, const float* __restrict__ bi2,
    float* __restrict__ out)
{
    extern __shared__ char L[];
    char*  Wb   = L + 65536;             // 2 bufs x 32768: [mat][hi/lo][row][256B]
    float* lgs  = (float*)(L + 131072);  // [2 c][128 l]
    float* wfl  = (float*)(L + 132096);  // [128]
    float* wred = (float*)(L + 132608);  // 4 floats

    const int t     = threadIdx.x;
    const int w     = t >> 6;            // 0..7
    const int lane  = t & 63;
    const int l15   = lane & 15;
    const int koff8 = (lane >> 4) * 8;
    const int koffb = koff8 * 2;

    const int bid  = blockIdx.x;
    const int b    = bid >> 3;
    const int sub  = bid & 7;
    const int term = sub >> 2;
    const int dq   = (sub >> 1) & 1;
    const int eo   = sub & 1;

    // W staging role: 128 threads per mat; 8 threads per 128-float row
    const int smat = t >> 7;             // 0..3
    const int srow = (t >> 3) & 15;      // 0..15
    const int skq  = t & 7;              // 0..7 -> k range skq*16..+15
    const float* Wsrc = (smat == 0) ? Wr1 : (smat == 1) ? Wi1
                      : (smat == 2) ? Wr2 : Wi2;

    F4 wpf[4];   // 16 floats = this thread's W tile slice

#define LOADW(NT)                                                             \
    {                                                                         \
        const float* p = Wsrc + (size_t)((NT) * 16 + srow) * ND + skq * 16;   \
        _Pragma("unroll")                                                     \
        for (int j = 0; j < 4; ++j)                                           \
            wpf[j].v = *(const float4*)&p[4 * j];                             \
    }

#define WRITEW(BUF)                                                           \
    {                                                                         \
        char* mb = Wb + (BUF) * 32768 + smat * 8192 + srow * 256;             \
        const int sw = (srow & 7) << 4;                                       \
        bf16x8 h0, l0, h1, l1;                                                \
        _Pragma("unroll")                                                     \
        for (int e = 0; e < 4; ++e) {                                         \
            short2 sa = bsplit(wpf[0].f[e]); h0[e] = sa.x; l0[e] = sa.y;      \
            short2 sb = bsplit(wpf[1].f[e]); h0[4 + e] = sb.x; l0[4 + e] = sb.y; \
            short2 sc = bsplit(wpf[2].f[e]); h1[e] = sc.x; l1[e] = sc.y;      \
            short2 sd = bsplit(wpf[3].f[e]); h1[4 + e] = sd.x; l1[4 + e] = sd.y; \
        }                                                                     \
        *(bf16x8*)(mb + ((skq * 32) ^ sw))             = h0;                  \
        *(bf16x8*)(mb + ((skq * 32 + 16) ^ sw))        = h1;                  \
        *(bf16x8*)(mb + 4096 + ((skq * 32) ^ sw))      = l0;                  \
        *(bf16x8*)(mb + 4096 + ((skq * 32 + 16) ^ sw)) = l1;                  \
    }

    // ---- A-fragments: X fp32 -> in-reg split, wave's own l-tile w ----
    bf16x8 axh[2][4], axl[2][4];   // [arr][ks]
    {
        const float* xs[2] = {xr, xi};
        const int arowg = b * NL + w * 16 + l15;
#pragma unroll
        for (int arr = 0; arr < 2; ++arr)
#pragma unroll
            for (int ks = 0; ks < 4; ++ks) {
                const float* p = xs[arr] + (size_t)arowg * ND + ks * 32 + koff8;
                F4 f0, f1;
                f0.v = *(const float4*)&p[0];
                f1.v = *(const float4*)&p[4];
                bf16x8 h, l;
#pragma unroll
                for (int e = 0; e < 4; ++e) {
                    short2 s = bsplit(f0.f[e]); h[e] = s.x; l[e] = s.y;
                }
#pragma unroll
                for (int e = 0; e < 4; ++e) {
                    short2 s = bsplit(f1.f[e]); h[4 + e] = s.x; l[4 + e] = s.y;
                }
                axh[arr][ks] = h;
                axl[arr][ks] = l;
            }
    }

    float pR[4] = {0.f, 0.f, 0.f, 0.f};
    float pI[4] = {0.f, 0.f, 0.f, 0.f};

    // ---- proj pipeline: 8 nt-steps, 1 barrier/step ----
    LOADW(0)
    WRITEW(0)
    __syncthreads();

    for (int nt = 0; nt < 8; ++nt) {
        if (nt < 7) LOADW(nt + 1)        // next tile's global loads in flight

        f32x4 acc[4];
#pragma unroll
        for (int m = 0; m < 4; ++m) acc[m] = (f32x4){0.f, 0.f, 0.f, 0.f};

        {
            const char* bufp = Wb + (nt & 1) * 32768 + l15 * 256;
            const int swr = (l15 & 7) << 4;
#pragma unroll
            for (int mat = 0; mat < 4; ++mat) {
                const int arr = mat & 1;
                const char* mb = bufp + mat * 8192;
#pragma unroll
                for (int ks = 0; ks < 4; ++ks) {
                    const int off = ((ks * 64) + koffb) ^ swr;
                    bf16x8 bh = *(const bf16x8*)(mb + off);
                    bf16x8 bl = *(const bf16x8*)(mb + 4096 + off);
                    acc[mat] = __builtin_amdgcn_mfma_f32_16x16x32_bf16(axh[arr][ks], bh, acc[mat], 0, 0, 0);
                    acc[mat] = __builtin_amdgcn_mfma_f32_16x16x32_bf16(axh[arr][ks], bl, acc[mat], 0, 0, 0);
                    acc[mat] = __builtin_amdgcn_mfma_f32_16x16x32_bf16(axl[arr][ks], bh, acc[mat], 0, 0, 0);
                }
            }
        }

        if (nt < 7) WRITEW((nt + 1) & 1) // other buffer: no collision with reads

        // epilogue: bias, logit partials, G -> LDS
        {
            const int d  = nt * 16 + l15;
            const float b0 = br1[d], b1 = bi1[d], b2 = br2[d], b3 = bi2[d];
            const int lb = w * 16 + (lane >> 4) * 4;
            ushort g2[4], g3[4];
#pragma unroll
            for (int r = 0; r < 4; ++r) {
                float y0 = acc[0][r] + b0;
                float y1 = acc[1][r] + b1;
                float y2 = acc[2][r] + b2;
                float y3 = acc[3][r] + b3;
                pR[r] += (y0 * y0 - y1 * y1) * (y2 * y2 - y3 * y3);
                pI[r] += 4.f * y0 * y1 * y2 * y3;
                g2[r] = f2bf(y2);
                g3[r] = f2bf(y3);
            }
            const int byte0 = d * 256 + ((lb * 2) ^ ((d & 7) << 4));
            *(unsigned int*)(L + byte0)             = (unsigned int)g2[0] | ((unsigned int)g2[1] << 16);
            *(unsigned int*)(L + byte0 + 4)         = (unsigned int)g2[2] | ((unsigned int)g2[3] << 16);
            *(unsigned int*)(L + 32768 + byte0)     = (unsigned int)g3[0] | ((unsigned int)g3[1] << 16);
            *(unsigned int*)(L + 32768 + byte0 + 4) = (unsigned int)g3[2] | ((unsigned int)g3[3] << 16);
        }

        __syncthreads();   // next step's compute reads the just-written buffer
    }

    // ---- logits: 16-lane shfl reduce -> lgs (wave owns its 16 rows) ----
#pragma unroll
    for (int off = 1; off < 16; off <<= 1)
#pragma unroll
        for (int r = 0; r < 4; ++r) {
            pR[r] += __shfl_xor(pR[r], off);
            pI[r] += __shfl_xor(pI[r], off);
        }
    if (l15 == 0) {
        const int row = w * 16 + (lane >> 4) * 4;
#pragma unroll
        for (int r = 0; r < 4; ++r) {
            lgs[row + r]       = pR[r];
            lgs[128 + row + r] = pI[r];
        }
    }
    __syncthreads();   // G + lgs visible block-wide

    // ---- softmax for this block's term (threads 0-127) ----
    float sv = 0.f, se = 0.f;
    if (t < 128) {
        sv = lgs[term * 128 + t];
        float m = sv;
#pragma unroll
        for (int off = 1; off < 64; off <<= 1) m = fmaxf(m, __shfl_xor(m, off));
        if (lane == 0) wred[w] = m;
    }
    __syncthreads();
    if (t < 128) {
        float m = fmaxf(wred[0], wred[1]);
        se = expf(sv - m);
        float s = se;
#pragma unroll
        for (int off = 1; off < 64; off <<= 1) s += __shfl_xor(s, off);
        if (lane == 0) wred[2 + w] = s;
    }
    __syncthreads();
    if (t < 128) wfl[t] = se / (wred[2] + wred[3]);
    __syncthreads();

    // ---- gram MFMA: wave w -> m-tile w&3, nt-pair w>>2 ----
    const int mt  = w & 3;
    const int ntp = w >> 2;

    f32x4 accP[2], accN[2];
#pragma unroll
    for (int n = 0; n < 2; ++n) {
        accP[n] = (f32x4){0.f, 0.f, 0.f, 0.f};
        accN[n] = (f32x4){0.f, 0.f, 0.f, 0.f};
    }

#pragma unroll
    for (int ks = 0; ks < 4; ++ks) {
        F4 w0, w1;
        w0.v = *(const float4*)&wfl[ks * 32 + koff8];
        w1.v = *(const float4*)&wfl[ks * 32 + koff8 + 4];
        float wv[8] = {w0.f[0], w0.f[1], w0.f[2], w0.f[3],
                       w1.f[0], w1.f[1], w1.f[2], w1.f[3]};

        const int ar = dq * 64 + mt * 16 + l15;
        const int ab = ar * 256 + (((ks * 64) + koffb) ^ ((ar & 7) << 4));
        BF8 a0; a0.v = *(const bf16x8*)(L + ab);
        BF8 a1; a1.v = *(const bf16x8*)(L + 32768 + ab);
        bf16x8 s0, s1;
#pragma unroll
        for (int e = 0; e < 8; ++e) {
            s0[e] = (short)f2bf(bf2f(a0.u[e]) * wv[e]);
            s1[e] = (short)f2bf(bf2f(a1.u[e]) * wv[e]);
        }
        bf16x8 aP = term ? s1 : s0;   // R: wr.r2 ; I: wi.i2
        bf16x8 aN = term ? s0 : s1;   // R: wr.i2 ; I: wi.r2

#pragma unroll
        for (int n = 0; n < 2; ++n) {
            const int br = eo * 64 + (ntp * 2 + n) * 16 + l15;
            const int bb = br * 256 + (((ks * 64) + koffb) ^ ((br & 7) << 4));
            bf16x8 b0 = *(const bf16x8*)(L + bb);
            bf16x8 b1 = *(const bf16x8*)(L + 32768 + bb);
            accP[n] = __builtin_amdgcn_mfma_f32_16x16x32_bf16(aP, b0, accP[n], 0, 0, 0);
            accN[n] = __builtin_amdgcn_mfma_f32_16x16x32_bf16(aN, b1, accN[n], 0, 0, 0);
        }
    }

    const float sgn = term ? 1.f : -1.f;
    float* dst = out + (size_t)term * NB * ND * ND + (size_t)b * ND * ND;
    const int rb = dq * 64 + mt * 16 + (lane >> 4) * 4;
#pragma unroll
    for (int n = 0; n < 2; ++n) {
        const int ec = eo * 64 + (ntp * 2 + n) * 16 + l15;
#pragma unroll
        for (int r = 0; r < 4; ++r)
            dst[(size_t)(rb + r) * ND + ec] = accP[n][r] + sgn * accN[n][r];
    }
}

extern "C" void kernel_launch(void* const* d_in, const int* in_sizes, int n_in,
                              void* d_out, int out_size, void* d_ws, size_t ws_size,
                              hipStream_t stream)
{
    const float* xr  = (const float*)d_in[0];
    const float* xi  = (const float*)d_in[1];
    const float* Wr1 = (const float*)d_in[2];
    const float* br1 = (const float*)d_in[3];
    const float* Wi1 = (const float*)d_in[4];
    const float* bi1 = (const float*)d_in[5];
    const float* Wr2 = (const float*)d_in[6];
    const float* br2 = (const float*)d_in[7];
    const float* Wi2 = (const float*)d_in[8];
    const float* bi2 = (const float*)d_in[9];

    (void)hipFuncSetAttribute((const void*)k_one,
                              hipFuncAttributeMaxDynamicSharedMemorySize, 132672);

    hipLaunchKernelGGL(k_one, dim3(256), dim3(512), 132672, stream,
                       xr, xi, Wr1, br1, Wi1, bi1, Wr2, br2, Wi2, bi2,
                       (float*)d_out);
}